// Round 1
// baseline (10658.884 us; speedup 1.0000x reference)
//
#include <hip/hip_runtime.h>
#include <cstdint>
#include <cstddef>

#define S_LEN 512
#define TCH   128
#define NCH   4
#define HDIM  128
#define G4    512
#define BATCH 256
#define NLAYER 10

__device__ __forceinline__ float fsig(float x) {
  return __builtin_amdgcn_rcpf(1.0f + __expf(-x));
}
__device__ __forceinline__ float ftanh(float x) {
  return fmaf(2.0f, __builtin_amdgcn_rcpf(1.0f + __expf(-2.0f * x)), -1.0f);
}

// ---------------------------------------------------------------------------
// Input-projection GEMM: XG[b][tt][g] = A[b, t0+tt, :] . W[g,:] + bih[g] + bhh[g]
// A row-major with row stride K (K=27 for x, K=128 for hidden seq).
// Tiles: BM=64 rows, BN=64 gates, BK<=64, 256 threads, 4x4 register tile.
// ---------------------------------------------------------------------------
template<int K>
__global__ __launch_bounds__(256, 4)
void gemm_xg(const float* __restrict__ A, const float* __restrict__ W,
             const float* __restrict__ bih, const float* __restrict__ bhh,
             float* __restrict__ XG, int t0)
{
  constexpr int BK  = (K < 64) ? K : 64;
  constexpr int NKC = K / BK;
  __shared__ float As[BK][68];   // [k][row], padded stride 68 (272B, 16B-aligned)
  __shared__ float Bs[BK][68];   // [k][col]
  const int tid = threadIdx.x;
  const int tx = tid & 15;
  const int ty = tid >> 4;
  const int rowBase = blockIdx.x * 64;
  const int colBase = blockIdx.y * 64;
  float acc[4][4] = {{0.f,0.f,0.f,0.f},{0.f,0.f,0.f,0.f},{0.f,0.f,0.f,0.f},{0.f,0.f,0.f,0.f}};

  for (int kc = 0; kc < NKC; ++kc) {
    const int kbase = kc * BK;
    for (int idx = tid; idx < 64 * BK; idx += 256) {
      int rr = idx / BK;
      int k  = idx - rr * BK;
      int r  = rowBase + rr;
      int bb = r >> 7;               // r / TCH
      int tt = r & (TCH - 1);
      As[k][rr] = A[(size_t)(bb * S_LEN + t0 + tt) * K + kbase + k];
    }
    for (int idx = tid; idx < 64 * BK; idx += 256) {
      int cc = idx / BK;
      int k  = idx - cc * BK;
      Bs[k][cc] = W[(size_t)(colBase + cc) * K + kbase + k];
    }
    __syncthreads();
    #pragma unroll 8
    for (int k = 0; k < BK; ++k) {
      const float4 av = *(const float4*)&As[k][ty * 4];
      const float4 bv = *(const float4*)&Bs[k][tx * 4];
      float a_[4] = {av.x, av.y, av.z, av.w};
      float b_[4] = {bv.x, bv.y, bv.z, bv.w};
      #pragma unroll
      for (int i = 0; i < 4; ++i) {
        #pragma unroll
        for (int jj = 0; jj < 4; ++jj)
          acc[i][jj] = fmaf(a_[i], b_[jj], acc[i][jj]);
      }
    }
    __syncthreads();
  }

  const int col0 = colBase + tx * 4;
  const float4 bi4 = *(const float4*)&bih[col0];
  const float4 bh4 = *(const float4*)&bhh[col0];
  const float b0 = bi4.x + bh4.x, b1 = bi4.y + bh4.y, b2 = bi4.z + bh4.z, b3 = bi4.w + bh4.w;
  #pragma unroll
  for (int i = 0; i < 4; ++i) {
    int r  = rowBase + ty * 4 + i;
    int bb = r >> 7;
    int tt = r & (TCH - 1);
    float4 o;
    o.x = acc[i][0] + b0; o.y = acc[i][1] + b1; o.z = acc[i][2] + b2; o.w = acc[i][3] + b3;
    *(float4*)&XG[(size_t)(bb * TCH + tt) * G4 + col0] = o;
  }
}

// ---------------------------------------------------------------------------
// Persistent per-batch-row LSTM scan over one chunk of TCH steps.
// 512 threads = 512 gate rows; W_hh row lives in 128 VGPRs per thread.
// h broadcast via uniform-address LDS reads; c in registers of threads 0..127.
// ---------------------------------------------------------------------------
__global__ __launch_bounds__(512, 2)
void lstm_scan(const float* __restrict__ XG, const float* __restrict__ Whh,
               float* __restrict__ Hout, float* __restrict__ c_state, int t0)
{
  const int b   = blockIdx.x;
  const int tid = threadIdx.x;
  __shared__ float h_s[HDIM];
  __shared__ float g_s[G4];
  float w[HDIM];
  {
    const float4* wr = (const float4*)(Whh + (size_t)tid * HDIM);
    #pragma unroll
    for (int kk = 0; kk < 32; ++kk) {
      float4 v = wr[kk];
      w[4*kk+0] = v.x; w[4*kk+1] = v.y; w[4*kk+2] = v.z; w[4*kk+3] = v.w;
    }
  }
  float c = 0.0f;
  if (tid < HDIM) {
    if (t0 == 0) {
      h_s[tid] = 0.0f;
    } else {
      h_s[tid] = Hout[(size_t)(b * S_LEN + t0 - 1) * HDIM + tid];
      c = c_state[b * HDIM + tid];
    }
  }
  __syncthreads();

  const float4* h4 = (const float4*)h_s;
  float xg_cur = XG[(size_t)(b * TCH) * G4 + tid];
  for (int tt = 0; tt < TCH; ++tt) {
    float xg = xg_cur;
    int tn = (tt + 1) & (TCH - 1);           // prefetch next step's xg (hidden under dot)
    xg_cur = XG[(size_t)(b * TCH + tn) * G4 + tid];
    float a0 = 0.f, a1 = 0.f, a2 = 0.f, a3 = 0.f;
    #pragma unroll
    for (int kk = 0; kk < 32; ++kk) {
      float4 hv = h4[kk];                    // uniform address -> LDS broadcast
      a0 = fmaf(w[4*kk+0], hv.x, a0);
      a1 = fmaf(w[4*kk+1], hv.y, a1);
      a2 = fmaf(w[4*kk+2], hv.z, a2);
      a3 = fmaf(w[4*kk+3], hv.w, a3);
    }
    g_s[tid] = xg + ((a0 + a1) + (a2 + a3));
    __syncthreads();
    if (tid < HDIM) {
      float gi = fsig(g_s[tid]);
      float gf = fsig(g_s[HDIM + tid]);
      float gg = ftanh(g_s[2*HDIM + tid]);
      float go = fsig(g_s[3*HDIM + tid]);
      c = fmaf(gf, c, gi * gg);
      float h = go * ftanh(c);
      h_s[tid] = h;
      Hout[(size_t)(b * S_LEN + t0 + tt) * HDIM + tid] = h;
    }
    __syncthreads();
  }
  if (tid < HDIM) c_state[b * HDIM + tid] = c;
}

// ---------------------------------------------------------------------------
// Attention pass 1: logits[b][t] = tanh(out[b,t,:]@attn_w^T + attn_b) . v_w + v_b
// attn_w row per thread in registers; out rows staged in LDS, broadcast-read.
// ---------------------------------------------------------------------------
__global__ __launch_bounds__(128)
void attn1(const float* __restrict__ Hs, const float* __restrict__ attn_w,
           const float* __restrict__ attn_b, const float* __restrict__ v_w,
           const float* __restrict__ v_b, float* __restrict__ logits)
{
  const int b  = blockIdx.x;
  const int tc = blockIdx.y;
  const int j  = threadIdx.x;   // 0..127
  float wreg[HDIM];
  {
    const float4* wr = (const float4*)(attn_w + (size_t)j * HDIM);
    #pragma unroll
    for (int kk = 0; kk < 32; ++kk) {
      float4 v = wr[kk];
      wreg[4*kk+0] = v.x; wreg[4*kk+1] = v.y; wreg[4*kk+2] = v.z; wreg[4*kk+3] = v.w;
    }
  }
  const float ab = attn_b[j];
  const float vw = v_w[j];
  const float vb = v_b[0];
  __shared__ float outs[16][HDIM];
  __shared__ float red[2];
  for (int t8 = 0; t8 < 8; ++t8) {
    const int tbase = tc * 128 + t8 * 16;
    for (int idx = j; idx < 16 * HDIM; idx += 128) {
      int rr = idx >> 7;
      int k  = idx & 127;
      outs[rr][k] = Hs[(size_t)(b * S_LEN + tbase + rr) * HDIM + k];
    }
    __syncthreads();
    for (int rr = 0; rr < 16; ++rr) {
      const float4* o4 = (const float4*)outs[rr];
      float a0 = 0.f, a1 = 0.f, a2 = 0.f, a3 = 0.f;
      #pragma unroll
      for (int kk = 0; kk < 32; ++kk) {
        float4 hv = o4[kk];
        a0 = fmaf(wreg[4*kk+0], hv.x, a0);
        a1 = fmaf(wreg[4*kk+1], hv.y, a1);
        a2 = fmaf(wreg[4*kk+2], hv.z, a2);
        a3 = fmaf(wreg[4*kk+3], hv.w, a3);
      }
      float s = ftanh(((a0 + a1) + (a2 + a3)) + ab) * vw;
      #pragma unroll
      for (int off = 1; off < 64; off <<= 1) s += __shfl_xor(s, off);
      if ((j & 63) == 0) red[j >> 6] = s;
      __syncthreads();
      if (j == 0) logits[b * S_LEN + tbase + rr] = red[0] + red[1] + vb;
      __syncthreads();
    }
  }
}

// ---------------------------------------------------------------------------
// Attention pass 2: softmax over time + context + final FC.
// ---------------------------------------------------------------------------
__global__ __launch_bounds__(128)
void attn2(const float* __restrict__ Hs, const float* __restrict__ logits,
           const float* __restrict__ fc_w, const float* __restrict__ fc_b,
           float* __restrict__ outp)
{
  const int b   = blockIdx.x;
  const int tid = threadIdx.x;
  __shared__ float pbuf[S_LEN];
  __shared__ float red[4];
  __shared__ float ctx_s[HDIM];
  float l0 = logits[b * S_LEN + tid];
  float l1 = logits[b * S_LEN + 128 + tid];
  float l2 = logits[b * S_LEN + 256 + tid];
  float l3 = logits[b * S_LEN + 384 + tid];
  float m = fmaxf(fmaxf(l0, l1), fmaxf(l2, l3));
  #pragma unroll
  for (int off = 1; off < 64; off <<= 1) m = fmaxf(m, __shfl_xor(m, off));
  if ((tid & 63) == 0) red[tid >> 6] = m;
  __syncthreads();
  m = fmaxf(red[0], red[1]);
  float p0 = __expf(l0 - m), p1 = __expf(l1 - m), p2 = __expf(l2 - m), p3 = __expf(l3 - m);
  pbuf[tid] = p0; pbuf[tid + 128] = p1; pbuf[tid + 256] = p2; pbuf[tid + 384] = p3;
  float sum = (p0 + p1) + (p2 + p3);
  #pragma unroll
  for (int off = 1; off < 64; off <<= 1) sum += __shfl_xor(sum, off);
  if ((tid & 63) == 0) red[2 + (tid >> 6)] = sum;
  __syncthreads();
  const float sinv = 1.0f / (red[2] + red[3]);
  float acc = 0.f;
  const float* hp = Hs + (size_t)b * S_LEN * HDIM + tid;
  #pragma unroll 4
  for (int t = 0; t < S_LEN; ++t) acc = fmaf(pbuf[t], hp[(size_t)t * HDIM], acc);
  ctx_s[tid] = acc * sinv;
  __syncthreads();
  if (tid < 7) {
    float a = fc_b[tid];
    const float* fw = fc_w + tid * HDIM;
    #pragma unroll 8
    for (int k = 0; k < HDIM; ++k) a = fmaf(ctx_s[k], fw[k], a);
    outp[b * 7 + tid] = a;
  }
}

// ---------------------------------------------------------------------------
extern "C" void kernel_launch(void* const* d_in, const int* in_sizes, int n_in,
                              void* d_out, int out_size, void* d_ws, size_t ws_size,
                              hipStream_t stream)
{
  const float* x      = (const float*)d_in[0];
  const float* w_ih0  = (const float*)d_in[1];
  const float* w_ih   = (const float*)d_in[2];
  const float* w_hh   = (const float*)d_in[3];
  const float* b_ih   = (const float*)d_in[4];
  const float* b_hh   = (const float*)d_in[5];
  const float* attn_w = (const float*)d_in[6];
  const float* attn_b = (const float*)d_in[7];
  const float* v_w    = (const float*)d_in[8];
  const float* v_b    = (const float*)d_in[9];
  const float* fc_w   = (const float*)d_in[10];
  const float* fc_b   = (const float*)d_in[11];
  float* outp = (float*)d_out;

  const size_t szXG = (size_t)BATCH * TCH * G4;    // floats
  const size_t szH  = (size_t)BATCH * S_LEN * HDIM;
  char* p = (char*)d_ws;
  float* XG = (float*)p;  p += szXG * 4;
  float* H0 = (float*)p;  p += szH * 4;
  float* H1 = (float*)p;  p += szH * 4;
  float* cst = (float*)p; p += (size_t)BATCH * HDIM * 4;
  float* lg  = (float*)p; p += (size_t)BATCH * S_LEN * 4;
  if ((size_t)(p - (char*)d_ws) > ws_size) return;  // ws too small: fail visibly

  for (int l = 0; l < NLAYER; ++l) {
    const float* Wih = (l == 0) ? w_ih0 : (w_ih + (size_t)(l - 1) * G4 * HDIM);
    const float* Ain = (l == 0) ? x : ((l & 1) ? H0 : H1);  // output of layer l-1
    float* Ho = (l & 1) ? H1 : H0;
    const float* bi = b_ih + l * G4;
    const float* bh = b_hh + l * G4;
    const float* Wh = w_hh + (size_t)l * G4 * HDIM;
    for (int cch = 0; cch < NCH; ++cch) {
      int t0 = cch * TCH;
      if (l == 0)
        gemm_xg<27><<<dim3(BATCH * TCH / 64, G4 / 64), 256, 0, stream>>>(x, Wih, bi, bh, XG, t0);
      else
        gemm_xg<128><<<dim3(BATCH * TCH / 64, G4 / 64), 256, 0, stream>>>(Ain, Wih, bi, bh, XG, t0);
      lstm_scan<<<BATCH, 512, 0, stream>>>(XG, Wh, Ho, cst, t0);
    }
  }
  const float* Hlast = H1;  // layer 9 (odd) writes H1
  attn1<<<dim3(BATCH, 4), 128, 0, stream>>>(Hlast, attn_w, attn_b, v_w, v_b, lg);
  attn2<<<BATCH, 128, 0, stream>>>(Hlast, lg, fc_w, fc_b, outp);
}